// Round 1
// baseline (610.517 us; speedup 1.0000x reference)
//
#include <hip/hip_runtime.h>
#include <hip/hip_bf16.h>
#include <cstdint>
#include <cstddef>

// Problem constants (fixed by reference)
#define T_TOK 8192
#define DDIM  1024
#define FDIM  4096
#define NEXP  8
#define CAP   2048   // int(2.0 * T / E)

typedef __bf16 bf16_t;
typedef __bf16 bf16x8 __attribute__((ext_vector_type(8)));
typedef __bf16 bf16x4 __attribute__((ext_vector_type(4)));
typedef float  f32x4  __attribute__((ext_vector_type(4)));

// async global->LDS, 16B per lane; lds dest must be wave-uniform base (lane*16 auto)
__device__ __forceinline__ void gload16(const void* g, void* l) {
  __builtin_amdgcn_global_load_lds(
      (const __attribute__((address_space(1))) unsigned int*)g,
      (__attribute__((address_space(3))) unsigned int*)l,
      16, 0, 0);
}

// ---------------- x fp32 -> bf16 ----------------
__global__ void conv_x_kernel(const float* __restrict__ x, bf16_t* __restrict__ xb) {
  int i = blockIdx.x * blockDim.x + threadIdx.x;   // float4 index, total T*D/4
  float4 v = ((const float4*)x)[i];
  bf16x4 o;
  o[0] = (bf16_t)v.x; o[1] = (bf16_t)v.y; o[2] = (bf16_t)v.z; o[3] = (bf16_t)v.w;
  *(bf16x4*)(xb + (size_t)i * 4) = o;
}

// ---------------- router: logits, softmax, argmax ----------------
__global__ void router_kernel(const float* __restrict__ x, const float* __restrict__ wsw,
                              const float* __restrict__ bsw, int* __restrict__ routes,
                              float* __restrict__ rpm, float* __restrict__ partial) {
  const int wv = threadIdx.x >> 6, lane = threadIdx.x & 63;
  const int t = blockIdx.x * 4 + wv;
  const float* xr = x + (size_t)t * DDIM;
  float a[8] = {0.f,0.f,0.f,0.f,0.f,0.f,0.f,0.f};
  for (int d = lane; d < DDIM; d += 64) {
    float xv = xr[d];
    const float4* wr = (const float4*)(wsw + d * 8);
    float4 w0 = wr[0], w1 = wr[1];
    a[0] += xv * w0.x; a[1] += xv * w0.y; a[2] += xv * w0.z; a[3] += xv * w0.w;
    a[4] += xv * w1.x; a[5] += xv * w1.y; a[6] += xv * w1.z; a[7] += xv * w1.w;
  }
#pragma unroll
  for (int e = 0; e < 8; ++e) {
#pragma unroll
    for (int off = 32; off > 0; off >>= 1) a[e] += __shfl_xor(a[e], off);
    a[e] += bsw[e];
  }
  float m = a[0]; int arg = 0;
#pragma unroll
  for (int e = 1; e < 8; ++e) { if (a[e] > m) { m = a[e]; arg = e; } }
  float p[8]; float s = 0.f;
#pragma unroll
  for (int e = 0; e < 8; ++e) { p[e] = expf(a[e] - m); s += p[e]; }
  float inv_s = 1.f / s;   // = softmax max since p[arg]=1
  __shared__ float pp[4][8];
  if (lane == 0) {
    routes[t] = arg;
    rpm[t] = inv_s;
#pragma unroll
    for (int e = 0; e < 8; ++e) pp[wv][e] = p[e] * inv_s;
  }
  __syncthreads();
  if (threadIdx.x < 8) {
    int e = threadIdx.x;
    partial[(size_t)blockIdx.x * 8 + e] = pp[0][e] + pp[1][e] + pp[2][e] + pp[3][e];
  }
}

// ---------------- deterministic reduce of per-block prob sums ----------------
__global__ void reduce_partials_kernel(const float* __restrict__ partial,
                                       float* __restrict__ out_rps) {
  int tid = threadIdx.x;           // 256
  int e = tid & 7, j0 = tid >> 3;  // 32 lanes per expert
  float s = 0.f;
  for (int j = j0; j < 2048; j += 32) s += partial[j * 8 + e];
  __shared__ float red[256];
  red[tid] = s;
  __syncthreads();
  if (tid < 8) {
    float t = 0.f;
    for (int k = 0; k < 32; ++k) t += red[tid + 8 * k];
    out_rps[tid] = t;
  }
}

// ---------------- queue-position scan + dispatch index build ----------------
__global__ void scan_kernel(const int* __restrict__ routes, int* __restrict__ inv,
                            int* __restrict__ counts_i, float* __restrict__ out_counts,
                            float* __restrict__ out_ndrop) {
  __shared__ int scnt[256][8];
  __shared__ int raw[8];
  int tid = threadIdx.x;
  int myr[32];
  int cnt[8] = {0,0,0,0,0,0,0,0};
  int tbase = tid * 32;
  for (int i = 0; i < 32; ++i) { int r = routes[tbase + i]; myr[i] = r; cnt[r]++; }
#pragma unroll
  for (int e = 0; e < 8; ++e) scnt[tid][e] = cnt[e];
  __syncthreads();
  if (tid < 8) {
    int run = 0;
    for (int j = 0; j < 256; ++j) { int v = scnt[j][tid]; scnt[j][tid] = run; run += v; }
    raw[tid] = run;
  }
  __syncthreads();
  int base[8];
#pragma unroll
  for (int e = 0; e < 8; ++e) base[e] = scnt[tid][e];
  for (int i = 0; i < 32; ++i) {
    int r = myr[i];
    int p = base[r]++;
    if (p < CAP) inv[r * CAP + p] = tbase + i;
  }
  if (tid < 8) {
    int c = min(raw[tid], CAP);
    counts_i[tid] = c;
    out_counts[tid] = (float)c;
  }
  if (tid == 0) {
    int kept = 0;
    for (int e = 0; e < 8; ++e) kept += min(raw[e], CAP);
    *out_ndrop = (float)(T_TOK - kept);
  }
}

// ---------------- transpose + fp32->bf16 convert (per expert slice) ----------------
// src: expert-major [R][C] fp32 ; dst: [C][R] bf16 (batch-local slice blockIdx.z)
__global__ void transpose_conv_kernel(const float* __restrict__ src, bf16_t* __restrict__ dst,
                                      int R, int C, int e0) {
  const float* s = src + (size_t)(e0 + blockIdx.z) * ((size_t)R * C);
  bf16_t* d = dst + (size_t)blockIdx.z * ((size_t)R * C);
  __shared__ float tile[64][65];
  int bx = blockIdx.x * 64, by = blockIdx.y * 64;   // bx over C, by over R
  int tx = threadIdx.x & 63, ty = threadIdx.x >> 6;
#pragma unroll
  for (int r = ty; r < 64; r += 4) tile[r][tx] = s[(size_t)(by + r) * C + bx + tx];
  __syncthreads();
#pragma unroll
  for (int r = ty; r < 64; r += 4) d[(size_t)(bx + r) * R + by + tx] = (bf16_t)tile[tx][r];
}

// ---------------- pass-through fill: final[t] = x[t] * rpm[t] ----------------
__global__ void fill_passthrough_kernel(const float* __restrict__ x, const float* __restrict__ rpm,
                                        float* __restrict__ outf) {
  int i = blockIdx.x * blockDim.x + threadIdx.x;   // float4 index
  int t = i >> 8;                                  // 256 float4 per row
  float r = rpm[t];
  float4 v = ((const float4*)x)[i];
  float4 o = {v.x * r, v.y * r, v.z * r, v.w * r};
  ((float4*)outf)[i] = o;
}

// ---------------- MFMA GEMM (m97 structure: 128x128 tile, BK=32) ----------------
// Computes D[m][c] = sum_k A[m][k] * B[c][k]  (both operands row-major, K-contiguous)
// MODE 1: A=W1T[F][D], B=x_bf gathered via inv, epilogue relu(+b1) -> h[c][f] bf16
// MODE 2: A=W2T[D][F], B=h[c][f],                epilogue (+b2)*rpm -> final[t][d] f32
template <int KDIM, int MODE>
__launch_bounds__(256)
__global__ void gemm_kernel(const bf16_t* __restrict__ Abase, const bf16_t* __restrict__ Bbase,
                            const int* __restrict__ inv, const int* __restrict__ counts_i,
                            const float* __restrict__ bias_all, const float* __restrict__ rpm,
                            void* __restrict__ outp, int e0) {
  constexpr int MDIM = (MODE == 1) ? FDIM : DDIM;
  const int z = blockIdx.z;
  const int e = e0 + z;
  const int cnt = counts_i[e];
  const int c0 = blockIdx.x * 128;
  if (c0 >= cnt) return;                    // count-limited dim: skip empty tiles
  const int m0 = blockIdx.y * 128;

  const bf16_t* A = Abase + (size_t)z * ((size_t)MDIM * KDIM);
  const float* bias = bias_all + (size_t)e * MDIM;

  __shared__ __align__(16) bf16_t Alds[128 * 32];
  __shared__ __align__(16) bf16_t Blds[128 * 32];

  const int tid = threadIdx.x;
  const int lane = tid & 63;
  const int wv = tid >> 6;
  const int wm = wv >> 1, wn = wv & 1;

  // staging: chunk q = i*256 + tid covers row q>>2, k-subchunk q&3 (8 bf16 = 16B)
  const bf16_t* aptr[2];
  const bf16_t* bptr[2];
#pragma unroll
  for (int i = 0; i < 2; ++i) {
    int q = i * 256 + tid;
    aptr[i] = A + (size_t)(m0 + (q >> 2)) * KDIM + (q & 3) * 8;
    int c = c0 + (q >> 2);
    if (MODE == 1) {
      int tok = inv[e * CAP + c];           // empty slots pre-zeroed -> token 0 (result unread)
      bptr[i] = Bbase + (size_t)tok * KDIM + (q & 3) * 8;
    } else {
      bptr[i] = Bbase + (size_t)z * ((size_t)CAP * KDIM) + (size_t)c * KDIM + (q & 3) * 8;
    }
  }
  char* ldsA0 = (char*)Alds + (size_t)(tid & 192) * 16;   // wave-uniform base
  char* ldsB0 = (char*)Blds + (size_t)(tid & 192) * 16;

  f32x4 acc[4][4];
#pragma unroll
  for (int i = 0; i < 4; ++i)
#pragma unroll
    for (int j = 0; j < 4; ++j) acc[i][j] = (f32x4){0.f, 0.f, 0.f, 0.f};

  const int l15 = lane & 15, l4 = lane >> 4;
  for (int k0 = 0; k0 < KDIM; k0 += 32) {
    gload16(aptr[0] + k0, ldsA0);
    gload16(aptr[1] + k0, ldsA0 + 4096);
    gload16(bptr[0] + k0, ldsB0);
    gload16(bptr[1] + k0, ldsB0 + 4096);
    __syncthreads();
    bf16x8 af[4], bfr[4];
#pragma unroll
    for (int mi = 0; mi < 4; ++mi)
      af[mi] = *(const bf16x8*)&Alds[(wm * 64 + mi * 16 + l15) * 32 + l4 * 8];
#pragma unroll
    for (int ni = 0; ni < 4; ++ni)
      bfr[ni] = *(const bf16x8*)&Blds[(wn * 64 + ni * 16 + l15) * 32 + l4 * 8];
#pragma unroll
    for (int mi = 0; mi < 4; ++mi)
#pragma unroll
      for (int ni = 0; ni < 4; ++ni)
        acc[mi][ni] = __builtin_amdgcn_mfma_f32_16x16x32_bf16(af[mi], bfr[ni], acc[mi][ni], 0, 0, 0);
    __syncthreads();
  }

  // D layout: col(c) = lane&15, row(m) = (lane>>4)*4 + reg  [verified m89/m91]
  if (MODE == 1) {
    bf16_t* h = (bf16_t*)outp + (size_t)z * ((size_t)CAP * FDIM);
#pragma unroll
    for (int ni = 0; ni < 4; ++ni) {
      int c = c0 + wn * 64 + ni * 16 + l15;
      bf16_t* hrow = h + (size_t)c * FDIM;
#pragma unroll
      for (int mi = 0; mi < 4; ++mi) {
        int fb = m0 + wm * 64 + mi * 16 + l4 * 4;
        const float4 bi = *(const float4*)&bias[fb];
        f32x4 v = acc[mi][ni];
        bf16x4 hv;
        hv[0] = (bf16_t)fmaxf(v[0] + bi.x, 0.f);
        hv[1] = (bf16_t)fmaxf(v[1] + bi.y, 0.f);
        hv[2] = (bf16_t)fmaxf(v[2] + bi.z, 0.f);
        hv[3] = (bf16_t)fmaxf(v[3] + bi.w, 0.f);
        *(bf16x4*)&hrow[fb] = hv;
      }
    }
  } else {
    float* finalp = (float*)outp;
#pragma unroll
    for (int ni = 0; ni < 4; ++ni) {
      int c = c0 + wn * 64 + ni * 16 + l15;
      if (c < cnt) {
        int tok = inv[e * CAP + c];
        float r = rpm[tok];
        float* orow = finalp + (size_t)tok * DDIM;
#pragma unroll
        for (int mi = 0; mi < 4; ++mi) {
          int db = m0 + wm * 64 + mi * 16 + l4 * 4;
          const float4 bi = *(const float4*)&bias[db];
          f32x4 v = acc[mi][ni];
          float4 o;
          o.x = (v[0] + bi.x) * r;
          o.y = (v[1] + bi.y) * r;
          o.z = (v[2] + bi.z) * r;
          o.w = (v[3] + bi.w) * r;
          *(float4*)&orow[db] = o;
        }
      }
    }
  }
}

// ---------------- host launcher ----------------
extern "C" void kernel_launch(void* const* d_in, const int* in_sizes, int n_in,
                              void* d_out, int out_size, void* d_ws, size_t ws_size,
                              hipStream_t stream) {
  (void)in_sizes; (void)n_in; (void)out_size;
  const float* x   = (const float*)d_in[0];
  const float* wsw = (const float*)d_in[1];
  const float* bsw = (const float*)d_in[2];
  const float* W1  = (const float*)d_in[3];
  const float* b1  = (const float*)d_in[4];
  const float* W2  = (const float*)d_in[5];
  const float* b2  = (const float*)d_in[6];

  float* out_final  = (float*)d_out;            // [T][D]
  float* out_counts = out_final + 8388608;      // [8]
  float* out_rps    = out_final + 8388616;      // [8]
  float* out_ndrop  = out_final + 8388624;      // [1]
  float* out_rpm    = out_final + 8388625;      // [T]

  char* ws = (char*)d_ws;
  size_t off = 0;
  auto carve = [&](size_t bytes) {
    char* p = ws + off;
    off += (bytes + 255) & ~(size_t)255;
    return p;
  };
  bf16_t* xbf     = (bf16_t*)carve((size_t)T_TOK * DDIM * 2);   // 16 MB
  int*    routes  = (int*)   carve((size_t)T_TOK * 4);
  int*    inv     = (int*)   carve((size_t)NEXP * CAP * 4);
  int*    counts_i= (int*)   carve((size_t)NEXP * 4);
  float*  partial = (float*) carve((size_t)2048 * 8 * 4);
  size_t fixed = off;
  const size_t PER_E = 2 * (size_t)FDIM * DDIM * 2 + (size_t)CAP * FDIM * 2; // W1T+W2T+h = 32MB
  int nb = 8;
  while (nb > 1 && fixed + (size_t)nb * PER_E > ws_size) nb >>= 1;
  bf16_t* W1T  = (bf16_t*)carve((size_t)nb * FDIM * DDIM * 2);
  bf16_t* W2T  = (bf16_t*)carve((size_t)nb * DDIM * FDIM * 2);
  bf16_t* hbuf = (bf16_t*)carve((size_t)nb * CAP * FDIM * 2);

  conv_x_kernel<<<T_TOK * DDIM / 4 / 256, 256, 0, stream>>>(x, xbf);
  router_kernel<<<T_TOK / 4, 256, 0, stream>>>(x, wsw, bsw, routes, out_rpm, partial);
  reduce_partials_kernel<<<1, 256, 0, stream>>>(partial, out_rps);
  hipMemsetAsync(inv, 0, (size_t)NEXP * CAP * 4, stream);
  scan_kernel<<<1, 256, 0, stream>>>(routes, inv, counts_i, out_counts, out_ndrop);
  fill_passthrough_kernel<<<T_TOK * DDIM / 4 / 256, 256, 0, stream>>>(x, out_rpm, out_final);

  for (int e0 = 0; e0 < NEXP; e0 += nb) {
    // W1 [e][D][F] -> W1T [F][D] bf16
    transpose_conv_kernel<<<dim3(FDIM / 64, DDIM / 64, nb), 256, 0, stream>>>(W1, W1T, DDIM, FDIM, e0);
    gemm_kernel<DDIM, 1><<<dim3(CAP / 128, FDIM / 128, nb), 256, 0, stream>>>(
        W1T, xbf, inv, counts_i, b1, nullptr, hbuf, e0);
    // W2 [e][F][D] -> W2T [D][F] bf16
    transpose_conv_kernel<<<dim3(DDIM / 64, FDIM / 64, nb), 256, 0, stream>>>(W2, W2T, FDIM, DDIM, e0);
    gemm_kernel<FDIM, 2><<<dim3(CAP / 128, DDIM / 128, nb), 256, 0, stream>>>(
        W2T, hbuf, inv, counts_i, b2, out_rpm, d_out, e0);
  }
}

// Round 2
// 547.717 us; speedup vs baseline: 1.1147x; 1.1147x over previous
//
#include <hip/hip_runtime.h>
#include <hip/hip_bf16.h>
#include <cstdint>
#include <cstddef>

// Problem constants (fixed by reference)
#define T_TOK 8192
#define DDIM  1024
#define FDIM  4096
#define NEXP  8
#define CAP   2048   // int(2.0 * T / E)

typedef __bf16 bf16_t;
typedef __bf16 bf16x8 __attribute__((ext_vector_type(8)));
typedef __bf16 bf16x4 __attribute__((ext_vector_type(4)));
typedef float  f32x4  __attribute__((ext_vector_type(4)));

// async global->LDS, 16B per lane; lds dest must be wave-uniform base (lane*16 auto)
__device__ __forceinline__ void gload16(const void* g, void* l) {
  __builtin_amdgcn_global_load_lds(
      (const __attribute__((address_space(1))) unsigned int*)g,
      (__attribute__((address_space(3))) unsigned int*)l,
      16, 0, 0);
}

// ---------------- x fp32 -> bf16 ----------------
__global__ void conv_x_kernel(const float* __restrict__ x, bf16_t* __restrict__ xb) {
  int i = blockIdx.x * blockDim.x + threadIdx.x;   // float4 index, total T*D/4
  float4 v = ((const float4*)x)[i];
  bf16x4 o;
  o[0] = (bf16_t)v.x; o[1] = (bf16_t)v.y; o[2] = (bf16_t)v.z; o[3] = (bf16_t)v.w;
  *(bf16x4*)(xb + (size_t)i * 4) = o;
}

// ---------------- router: logits, softmax, argmax ----------------
__global__ void router_kernel(const float* __restrict__ x, const float* __restrict__ wsw,
                              const float* __restrict__ bsw, int* __restrict__ routes,
                              float* __restrict__ rpm, float* __restrict__ partial) {
  const int wv = threadIdx.x >> 6, lane = threadIdx.x & 63;
  const int t = blockIdx.x * 4 + wv;
  const float* xr = x + (size_t)t * DDIM;
  float a[8] = {0.f,0.f,0.f,0.f,0.f,0.f,0.f,0.f};
  for (int d = lane; d < DDIM; d += 64) {
    float xv = xr[d];
    const float4* wr = (const float4*)(wsw + d * 8);
    float4 w0 = wr[0], w1 = wr[1];
    a[0] += xv * w0.x; a[1] += xv * w0.y; a[2] += xv * w0.z; a[3] += xv * w0.w;
    a[4] += xv * w1.x; a[5] += xv * w1.y; a[6] += xv * w1.z; a[7] += xv * w1.w;
  }
#pragma unroll
  for (int e = 0; e < 8; ++e) {
#pragma unroll
    for (int off = 32; off > 0; off >>= 1) a[e] += __shfl_xor(a[e], off);
    a[e] += bsw[e];
  }
  float m = a[0]; int arg = 0;
#pragma unroll
  for (int e = 1; e < 8; ++e) { if (a[e] > m) { m = a[e]; arg = e; } }
  float p[8]; float s = 0.f;
#pragma unroll
  for (int e = 0; e < 8; ++e) { p[e] = expf(a[e] - m); s += p[e]; }
  float inv_s = 1.f / s;   // = softmax max since p[arg]=1
  __shared__ float pp[4][8];
  if (lane == 0) {
    routes[t] = arg;
    rpm[t] = inv_s;
#pragma unroll
    for (int e = 0; e < 8; ++e) pp[wv][e] = p[e] * inv_s;
  }
  __syncthreads();
  if (threadIdx.x < 8) {
    int e = threadIdx.x;
    partial[(size_t)blockIdx.x * 8 + e] = pp[0][e] + pp[1][e] + pp[2][e] + pp[3][e];
  }
}

// ---------------- deterministic reduce of per-block prob sums ----------------
__global__ void reduce_partials_kernel(const float* __restrict__ partial,
                                       float* __restrict__ out_rps) {
  int tid = threadIdx.x;           // 256
  int e = tid & 7, j0 = tid >> 3;  // 32 lanes per expert
  float s = 0.f;
  for (int j = j0; j < 2048; j += 32) s += partial[j * 8 + e];
  __shared__ float red[256];
  red[tid] = s;
  __syncthreads();
  if (tid < 8) {
    float t = 0.f;
    for (int k = 0; k < 32; ++k) t += red[tid + 8 * k];
    out_rps[tid] = t;
  }
}

// ---------------- queue-position scan + dispatch index build ----------------
__global__ void scan_kernel(const int* __restrict__ routes, int* __restrict__ inv,
                            int* __restrict__ counts_i, float* __restrict__ out_counts,
                            float* __restrict__ out_ndrop) {
  __shared__ int scnt[256][8];
  __shared__ int raw[8];
  int tid = threadIdx.x;
  int myr[32];
  int cnt[8] = {0,0,0,0,0,0,0,0};
  int tbase = tid * 32;
  for (int i = 0; i < 32; ++i) { int r = routes[tbase + i]; myr[i] = r; cnt[r]++; }
#pragma unroll
  for (int e = 0; e < 8; ++e) scnt[tid][e] = cnt[e];
  __syncthreads();
  if (tid < 8) {
    int run = 0;
    for (int j = 0; j < 256; ++j) { int v = scnt[j][tid]; scnt[j][tid] = run; run += v; }
    raw[tid] = run;
  }
  __syncthreads();
  int base[8];
#pragma unroll
  for (int e = 0; e < 8; ++e) base[e] = scnt[tid][e];
  for (int i = 0; i < 32; ++i) {
    int r = myr[i];
    int p = base[r]++;
    if (p < CAP) inv[r * CAP + p] = tbase + i;
  }
  if (tid < 8) {
    int c = min(raw[tid], CAP);
    counts_i[tid] = c;
    out_counts[tid] = (float)c;
  }
  if (tid == 0) {
    int kept = 0;
    for (int e = 0; e < 8; ++e) kept += min(raw[e], CAP);
    *out_ndrop = (float)(T_TOK - kept);
  }
}

// ---------------- transpose + fp32->bf16 convert (per expert slice) ----------------
// src: expert-major [R][C] fp32 ; dst: [C][R] bf16 (batch-local slice blockIdx.z)
// vectorized: float4 global reads, bf16x8 global writes
__global__ void transpose_conv_kernel(const float* __restrict__ src, bf16_t* __restrict__ dst,
                                      int R, int C, int e0) {
  const float* s = src + (size_t)(e0 + blockIdx.z) * ((size_t)R * C);
  bf16_t* d = dst + (size_t)blockIdx.z * ((size_t)R * C);
  __shared__ float tile[64][65];
  int bx = blockIdx.x * 64, by = blockIdx.y * 64;   // bx over C, by over R
  int c4 = (threadIdx.x & 15) * 4;
  int r0 = threadIdx.x >> 4;        // 16 rows per pass, 4 passes
#pragma unroll
  for (int p = 0; p < 4; ++p) {
    int r = r0 + p * 16;
    float4 v = *(const float4*)&s[(size_t)(by + r) * C + bx + c4];
    tile[r][c4] = v.x; tile[r][c4 + 1] = v.y; tile[r][c4 + 2] = v.z; tile[r][c4 + 3] = v.w;
  }
  __syncthreads();
  int r8 = (threadIdx.x & 7) * 8;
  int cw = threadIdx.x >> 3;        // 32 cols per pass, 2 passes
#pragma unroll
  for (int p = 0; p < 2; ++p) {
    int c = cw + p * 32;
    bf16x8 o;
#pragma unroll
    for (int j = 0; j < 8; ++j) o[j] = (bf16_t)tile[r8 + j][c];
    *(bf16x8*)&d[(size_t)(bx + c) * R + by + r8] = o;
  }
}

// ---------------- pass-through fill: final[t] = x[t] * rpm[t] ----------------
__global__ void fill_passthrough_kernel(const float* __restrict__ x, const float* __restrict__ rpm,
                                        float* __restrict__ outf) {
  int i = blockIdx.x * blockDim.x + threadIdx.x;   // float4 index
  int t = i >> 8;                                  // 256 float4 per row
  float r = rpm[t];
  float4 v = ((const float4*)x)[i];
  float4 o = {v.x * r, v.y * r, v.z * r, v.w * r};
  ((float4*)outf)[i] = o;
}

// ---------------- MFMA GEMM: 128x128 tile, BK=32, 2-phase double-buffered LDS ----------------
// Computes D[m][c] = sum_k A[m][k] * B[c][k]  (both operands row-major, K-contiguous)
// MODE 1: A=W1T[F][D], B=x_bf gathered via inv, epilogue relu(+b1) -> h[c][f] bf16
// MODE 2: A=W2T[D][F], B=h[c][f],                epilogue (+b2)*rpm -> final[t][d] f32
template <int KDIM, int MODE>
__launch_bounds__(256)
__global__ void gemm_kernel(const bf16_t* __restrict__ Abase, const bf16_t* __restrict__ Bbase,
                            const int* __restrict__ inv, const int* __restrict__ counts_i,
                            const float* __restrict__ bias_all, const float* __restrict__ rpm,
                            void* __restrict__ outp, int e0) {
  constexpr int MDIM = (MODE == 1) ? FDIM : DDIM;
  const int z = blockIdx.z;
  const int e = e0 + z;
  const int cnt = counts_i[e];
  const int c0 = blockIdx.x * 128;
  if (c0 >= cnt) return;                    // count-limited dim: skip empty tiles
  const int m0 = blockIdx.y * 128;

  const bf16_t* A = Abase + (size_t)z * ((size_t)MDIM * KDIM);
  const float* bias = bias_all + (size_t)e * MDIM;

  __shared__ __align__(16) bf16_t Alds[2][128 * 32];
  __shared__ __align__(16) bf16_t Blds[2][128 * 32];

  const int tid = threadIdx.x;
  const int lane = tid & 63;
  const int wv = tid >> 6;
  const int wm = wv >> 1, wn = wv & 1;

  // staging: chunk q = i*256 + tid covers row q>>2, k-subchunk q&3 (8 bf16 = 16B)
  const bf16_t* aptr[2];
  const bf16_t* bptr[2];
#pragma unroll
  for (int i = 0; i < 2; ++i) {
    int q = i * 256 + tid;
    aptr[i] = A + (size_t)(m0 + (q >> 2)) * KDIM + (q & 3) * 8;
    int c = c0 + (q >> 2);
    if (MODE == 1) {
      int tok = inv[e * CAP + c];           // empty slots pre-zeroed -> token 0 (result unread)
      bptr[i] = Bbase + (size_t)tok * KDIM + (q & 3) * 8;
    } else {
      bptr[i] = Bbase + (size_t)z * ((size_t)CAP * KDIM) + (size_t)c * KDIM + (q & 3) * 8;
    }
  }
  const int wbase = (tid & 192) * 16;       // wave-uniform LDS byte base within buffer

  auto stage = [&](int buf, int k0) {
    char* la = (char*)Alds + buf * 8192 + wbase;
    char* lb = (char*)Blds + buf * 8192 + wbase;
    gload16(aptr[0] + k0, la);
    gload16(aptr[1] + k0, la + 4096);
    gload16(bptr[0] + k0, lb);
    gload16(bptr[1] + k0, lb + 4096);
  };

  f32x4 acc[4][4];
#pragma unroll
  for (int i = 0; i < 4; ++i)
#pragma unroll
    for (int j = 0; j < 4; ++j) acc[i][j] = (f32x4){0.f, 0.f, 0.f, 0.f};

  const int l15 = lane & 15, l4 = lane >> 4;

  stage(0, 0);
  __syncthreads();                          // drains vmcnt(0): buf0 ready

  for (int k0 = 0; k0 < KDIM; k0 += 32) {
    const int cur = (k0 >> 5) & 1;
    if (k0 + 32 < KDIM) stage(cur ^ 1, k0 + 32);   // prefetch next tile FIRST
    bf16x8 af[4], bfr[4];
#pragma unroll
    for (int mi = 0; mi < 4; ++mi)
      af[mi] = *(const bf16x8*)&Alds[cur][(wm * 64 + mi * 16 + l15) * 32 + l4 * 8];
#pragma unroll
    for (int ni = 0; ni < 4; ++ni)
      bfr[ni] = *(const bf16x8*)&Blds[cur][(wn * 64 + ni * 16 + l15) * 32 + l4 * 8];
#pragma unroll
    for (int mi = 0; mi < 4; ++mi)
#pragma unroll
      for (int ni = 0; ni < 4; ++ni)
        acc[mi][ni] = __builtin_amdgcn_mfma_f32_16x16x32_bf16(af[mi], bfr[ni], acc[mi][ni], 0, 0, 0);
    __syncthreads();                        // one drain+barrier per K-step (next buf ready)
  }

  // D layout: col(c) = lane&15, row(m) = (lane>>4)*4 + reg  [verified m89/m91]
  if (MODE == 1) {
    bf16_t* h = (bf16_t*)outp + (size_t)z * ((size_t)CAP * FDIM);
#pragma unroll
    for (int ni = 0; ni < 4; ++ni) {
      int c = c0 + wn * 64 + ni * 16 + l15;
      bf16_t* hrow = h + (size_t)c * FDIM;
#pragma unroll
      for (int mi = 0; mi < 4; ++mi) {
        int fb = m0 + wm * 64 + mi * 16 + l4 * 4;
        const float4 bi = *(const float4*)&bias[fb];
        f32x4 v = acc[mi][ni];
        bf16x4 hv;
        hv[0] = (bf16_t)fmaxf(v[0] + bi.x, 0.f);
        hv[1] = (bf16_t)fmaxf(v[1] + bi.y, 0.f);
        hv[2] = (bf16_t)fmaxf(v[2] + bi.z, 0.f);
        hv[3] = (bf16_t)fmaxf(v[3] + bi.w, 0.f);
        *(bf16x4*)&hrow[fb] = hv;
      }
    }
  } else {
    float* finalp = (float*)outp;
#pragma unroll
    for (int ni = 0; ni < 4; ++ni) {
      int c = c0 + wn * 64 + ni * 16 + l15;
      if (c < cnt) {
        int tok = inv[e * CAP + c];
        float r = rpm[tok];
        float* orow = finalp + (size_t)tok * DDIM;
#pragma unroll
        for (int mi = 0; mi < 4; ++mi) {
          int db = m0 + wm * 64 + mi * 16 + l4 * 4;
          const float4 bi = *(const float4*)&bias[db];
          f32x4 v = acc[mi][ni];
          float4 o;
          o.x = (v[0] + bi.x) * r;
          o.y = (v[1] + bi.y) * r;
          o.z = (v[2] + bi.z) * r;
          o.w = (v[3] + bi.w) * r;
          *(float4*)&orow[db] = o;
        }
      }
    }
  }
}

// ---------------- host launcher ----------------
extern "C" void kernel_launch(void* const* d_in, const int* in_sizes, int n_in,
                              void* d_out, int out_size, void* d_ws, size_t ws_size,
                              hipStream_t stream) {
  (void)in_sizes; (void)n_in; (void)out_size;
  const float* x   = (const float*)d_in[0];
  const float* wsw = (const float*)d_in[1];
  const float* bsw = (const float*)d_in[2];
  const float* W1  = (const float*)d_in[3];
  const float* b1  = (const float*)d_in[4];
  const float* W2  = (const float*)d_in[5];
  const float* b2  = (const float*)d_in[6];

  float* out_final  = (float*)d_out;            // [T][D]
  float* out_counts = out_final + 8388608;      // [8]
  float* out_rps    = out_final + 8388616;      // [8]
  float* out_ndrop  = out_final + 8388624;      // [1]
  float* out_rpm    = out_final + 8388625;      // [T]

  char* ws = (char*)d_ws;
  size_t off = 0;
  auto carve = [&](size_t bytes) {
    char* p = ws + off;
    off += (bytes + 255) & ~(size_t)255;
    return p;
  };
  bf16_t* xbf     = (bf16_t*)carve((size_t)T_TOK * DDIM * 2);   // 16 MB
  int*    routes  = (int*)   carve((size_t)T_TOK * 4);
  int*    inv     = (int*)   carve((size_t)NEXP * CAP * 4);
  int*    counts_i= (int*)   carve((size_t)NEXP * 4);
  float*  partial = (float*) carve((size_t)2048 * 8 * 4);
  size_t fixed = off;
  const size_t PER_E = 2 * (size_t)FDIM * DDIM * 2 + (size_t)CAP * FDIM * 2; // W1T+W2T+h = 32MB
  int nb = 8;
  while (nb > 1 && fixed + (size_t)nb * PER_E > ws_size) nb >>= 1;
  bf16_t* W1T  = (bf16_t*)carve((size_t)nb * FDIM * DDIM * 2);
  bf16_t* W2T  = (bf16_t*)carve((size_t)nb * DDIM * FDIM * 2);
  bf16_t* hbuf = (bf16_t*)carve((size_t)nb * CAP * FDIM * 2);

  conv_x_kernel<<<T_TOK * DDIM / 4 / 256, 256, 0, stream>>>(x, xbf);
  router_kernel<<<T_TOK / 4, 256, 0, stream>>>(x, wsw, bsw, routes, out_rpm, partial);
  reduce_partials_kernel<<<1, 256, 0, stream>>>(partial, out_rps);
  hipMemsetAsync(inv, 0, (size_t)NEXP * CAP * 4, stream);
  scan_kernel<<<1, 256, 0, stream>>>(routes, inv, counts_i, out_counts, out_ndrop);
  fill_passthrough_kernel<<<T_TOK * DDIM / 4 / 256, 256, 0, stream>>>(x, out_rpm, out_final);

  for (int e0 = 0; e0 < NEXP; e0 += nb) {
    // W1 [e][D][F] -> W1T [F][D] bf16
    transpose_conv_kernel<<<dim3(FDIM / 64, DDIM / 64, nb), 256, 0, stream>>>(W1, W1T, DDIM, FDIM, e0);
    gemm_kernel<DDIM, 1><<<dim3(CAP / 128, FDIM / 128, nb), 256, 0, stream>>>(
        W1T, xbf, inv, counts_i, b1, nullptr, hbuf, e0);
    // W2 [e][F][D] -> W2T [D][F] bf16
    transpose_conv_kernel<<<dim3(DDIM / 64, FDIM / 64, nb), 256, 0, stream>>>(W2, W2T, FDIM, DDIM, e0);
    gemm_kernel<FDIM, 2><<<dim3(CAP / 128, DDIM / 128, nb), 256, 0, stream>>>(
        W2T, hbuf, inv, counts_i, b2, out_rpm, d_out, e0);
  }
}

// Round 3
// 461.043 us; speedup vs baseline: 1.3242x; 1.1880x over previous
//
#include <hip/hip_runtime.h>
#include <hip/hip_bf16.h>
#include <cstdint>
#include <cstddef>

// Problem constants (fixed by reference)
#define T_TOK 8192
#define DDIM  1024
#define FDIM  4096
#define NEXP  8
#define CAP   2048   // int(2.0 * T / E)

typedef __bf16 bf16_t;
typedef __bf16 bf16x8 __attribute__((ext_vector_type(8)));
typedef __bf16 bf16x4 __attribute__((ext_vector_type(4)));
typedef float  f32x4  __attribute__((ext_vector_type(4)));

// async global->LDS, 16B per lane; lds dest must be wave-uniform base (lane*16 auto)
__device__ __forceinline__ void gload16(const void* g, void* l) {
  __builtin_amdgcn_global_load_lds(
      (const __attribute__((address_space(1))) unsigned int*)g,
      (__attribute__((address_space(3))) unsigned int*)l,
      16, 0, 0);
}

#define VMWAIT(N) asm volatile("s_waitcnt vmcnt(" #N ")" ::: "memory")
#define BARR asm volatile("s_barrier" ::: "memory")

// ---------------- x fp32 -> bf16 ----------------
__global__ void conv_x_kernel(const float* __restrict__ x, bf16_t* __restrict__ xb) {
  int i = blockIdx.x * blockDim.x + threadIdx.x;   // float4 index, total T*D/4
  float4 v = ((const float4*)x)[i];
  bf16x4 o;
  o[0] = (bf16_t)v.x; o[1] = (bf16_t)v.y; o[2] = (bf16_t)v.z; o[3] = (bf16_t)v.w;
  *(bf16x4*)(xb + (size_t)i * 4) = o;
}

// ---------------- router: logits, softmax, argmax ----------------
__global__ void router_kernel(const float* __restrict__ x, const float* __restrict__ wsw,
                              const float* __restrict__ bsw, int* __restrict__ routes,
                              float* __restrict__ rpm, float* __restrict__ partial) {
  const int wv = threadIdx.x >> 6, lane = threadIdx.x & 63;
  const int t = blockIdx.x * 4 + wv;
  const float* xr = x + (size_t)t * DDIM;
  float a[8] = {0.f,0.f,0.f,0.f,0.f,0.f,0.f,0.f};
  for (int d = lane; d < DDIM; d += 64) {
    float xv = xr[d];
    const float4* wr = (const float4*)(wsw + d * 8);
    float4 w0 = wr[0], w1 = wr[1];
    a[0] += xv * w0.x; a[1] += xv * w0.y; a[2] += xv * w0.z; a[3] += xv * w0.w;
    a[4] += xv * w1.x; a[5] += xv * w1.y; a[6] += xv * w1.z; a[7] += xv * w1.w;
  }
#pragma unroll
  for (int e = 0; e < 8; ++e) {
#pragma unroll
    for (int off = 32; off > 0; off >>= 1) a[e] += __shfl_xor(a[e], off);
    a[e] += bsw[e];
  }
  float m = a[0]; int arg = 0;
#pragma unroll
  for (int e = 1; e < 8; ++e) { if (a[e] > m) { m = a[e]; arg = e; } }
  float p[8]; float s = 0.f;
#pragma unroll
  for (int e = 0; e < 8; ++e) { p[e] = expf(a[e] - m); s += p[e]; }
  float inv_s = 1.f / s;   // = softmax max since p[arg]=1
  __shared__ float pp[4][8];
  if (lane == 0) {
    routes[t] = arg;
    rpm[t] = inv_s;
#pragma unroll
    for (int e = 0; e < 8; ++e) pp[wv][e] = p[e] * inv_s;
  }
  __syncthreads();
  if (threadIdx.x < 8) {
    int e = threadIdx.x;
    partial[(size_t)blockIdx.x * 8 + e] = pp[0][e] + pp[1][e] + pp[2][e] + pp[3][e];
  }
}

// ---------------- deterministic reduce of per-block prob sums ----------------
__global__ void reduce_partials_kernel(const float* __restrict__ partial,
                                       float* __restrict__ out_rps) {
  int tid = threadIdx.x;           // 256
  int e = tid & 7, j0 = tid >> 3;  // 32 lanes per expert
  float s = 0.f;
  for (int j = j0; j < 2048; j += 32) s += partial[j * 8 + e];
  __shared__ float red[256];
  red[tid] = s;
  __syncthreads();
  if (tid < 8) {
    float t = 0.f;
    for (int k = 0; k < 32; ++k) t += red[tid + 8 * k];
    out_rps[tid] = t;
  }
}

// ---------------- queue-position scan + dispatch index build ----------------
__global__ void scan_kernel(const int* __restrict__ routes, int* __restrict__ inv,
                            int* __restrict__ counts_i, float* __restrict__ out_counts,
                            float* __restrict__ out_ndrop) {
  __shared__ int scnt[256][8];
  __shared__ int raw[8];
  int tid = threadIdx.x;
  int myr[32];
  int cnt[8] = {0,0,0,0,0,0,0,0};
  int tbase = tid * 32;
  for (int i = 0; i < 32; ++i) { int r = routes[tbase + i]; myr[i] = r; cnt[r]++; }
#pragma unroll
  for (int e = 0; e < 8; ++e) scnt[tid][e] = cnt[e];
  __syncthreads();
  if (tid < 8) {
    int run = 0;
    for (int j = 0; j < 256; ++j) { int v = scnt[j][tid]; scnt[j][tid] = run; run += v; }
    raw[tid] = run;
  }
  __syncthreads();
  int base[8];
#pragma unroll
  for (int e = 0; e < 8; ++e) base[e] = scnt[tid][e];
  for (int i = 0; i < 32; ++i) {
    int r = myr[i];
    int p = base[r]++;
    if (p < CAP) inv[r * CAP + p] = tbase + i;
  }
  if (tid < 8) {
    int c = min(raw[tid], CAP);
    counts_i[tid] = c;
    out_counts[tid] = (float)c;
  }
  if (tid == 0) {
    int kept = 0;
    for (int e = 0; e < 8; ++e) kept += min(raw[e], CAP);
    *out_ndrop = (float)(T_TOK - kept);
  }
}

// ---------------- transpose + fp32->bf16 convert (per expert slice) ----------------
__global__ void transpose_conv_kernel(const float* __restrict__ src, bf16_t* __restrict__ dst,
                                      int R, int C, int e0) {
  const float* s = src + (size_t)(e0 + blockIdx.z) * ((size_t)R * C);
  bf16_t* d = dst + (size_t)blockIdx.z * ((size_t)R * C);
  __shared__ float tile[64][65];
  int bx = blockIdx.x * 64, by = blockIdx.y * 64;   // bx over C, by over R
  int c4 = (threadIdx.x & 15) * 4;
  int r0 = threadIdx.x >> 4;        // 16 rows per pass, 4 passes
#pragma unroll
  for (int p = 0; p < 4; ++p) {
    int r = r0 + p * 16;
    float4 v = *(const float4*)&s[(size_t)(by + r) * C + bx + c4];
    tile[r][c4] = v.x; tile[r][c4 + 1] = v.y; tile[r][c4 + 2] = v.z; tile[r][c4 + 3] = v.w;
  }
  __syncthreads();
  int r8 = (threadIdx.x & 7) * 8;
  int cw = threadIdx.x >> 3;        // 32 cols per pass, 2 passes
#pragma unroll
  for (int p = 0; p < 2; ++p) {
    int c = cw + p * 32;
    bf16x8 o;
#pragma unroll
    for (int j = 0; j < 8; ++j) o[j] = (bf16_t)tile[r8 + j][c];
    *(bf16x8*)&d[(size_t)(bx + c) * R + by + r8] = o;
  }
}

// ---------------- pass-through fill: final[t] = x[t] * rpm[t] ----------------
__global__ void fill_passthrough_kernel(const float* __restrict__ x, const float* __restrict__ rpm,
                                        float* __restrict__ outf) {
  int i = blockIdx.x * blockDim.x + threadIdx.x;   // float4 index
  int t = i >> 8;                                  // 256 float4 per row
  float r = rpm[t];
  float4 v = ((const float4*)x)[i];
  float4 o = {v.x * r, v.y * r, v.z * r, v.w * r};
  ((float4*)outf)[i] = o;
}

// ---------------- MFMA GEMM: BMx256 tile, BK=32, 4-slot LDS ring, counted vmcnt ----------------
// D[m][c] = sum_k A[m][k] * B[c][k]  (both row-major K-contiguous)
// 8 waves (2M x 4N). Per phase (1 K-tile of 32): issue L gload_lds for tile j+3,
// vmcnt(3L), barrier, swizzled ds_read (12 or 8 x b128), 32/16 MFMA, barrier.
// LDS swizzle: 16B-granule cg ^= (row>>1)&3 within 64B rows (conflict-free b128 reads);
// content pre-swizzled at the GLOBAL source (global_load_lds writes linearly).
// NOTE: loop-body VMEM ops are EXACTLY the gload_lds calls (vmcnt counts depend on it).
// MODE 1: A=W1T[F][D], B=xbf gathered via inv -> relu(+b1) -> h bf16
// MODE 2: A=W2T[D][F], B=h                    -> (+b2)*rpm scattered -> final f32
template <int KDIM, int MODE, int BM>
__launch_bounds__(512, 2)
__global__ void gemm8_kernel(const bf16_t* __restrict__ Abase, const bf16_t* __restrict__ Bbase,
                             const int* __restrict__ inv, const int* __restrict__ counts_i,
                             const float* __restrict__ bias_all, const float* __restrict__ rpm,
                             void* __restrict__ outp, int e0) {
  constexpr int MDIM = (MODE == 1) ? FDIM : DDIM;
  constexpr int NT = KDIM / 32;      // phases
  constexpr int NA = BM / 128;       // A gload_lds per wave per phase (2 or 1)
  constexpr int ABYTES = BM * 64;    // A slot bytes (rows of 64B)
  constexpr int SLOT = ABYTES + 16384;
  constexpr int MF = BM / 32;        // M-frags per wave (8 or 4)
  extern __shared__ char smem[];

  // T1: XCD-chunked bijective swizzle (nwg % 8 == 0 by construction)
  const int nx = gridDim.x, ny = gridDim.y;
  const int nwg = nx * ny * gridDim.z;
  const int flat = blockIdx.x + nx * (blockIdx.y + ny * blockIdx.z);
  const int nf = (flat & 7) * (nwg >> 3) + (flat >> 3);
  const int bx = nf % nx;
  const int tmp = nf / nx;
  const int by = tmp % ny, bz = tmp / ny;

  const int e = e0 + bz;
  const int cnt = counts_i[e];
  const int c0 = bx * 256;
  if (c0 >= cnt) return;             // uniform early-exit (before any barrier)
  const int m0 = by * BM;

  const bf16_t* A = Abase + (size_t)bz * ((size_t)MDIM * KDIM);
  const float* bias = bias_all + (size_t)e * MDIM;

  const int tid = threadIdx.x, lane = tid & 63, w = tid >> 6;
  const int l15 = lane & 15, l4 = lane >> 4;
  const int wm = w >> 2, wn = w & 3;

  // ---- staging sources (pre-swizzled global addresses), fixed per thread ----
  const bf16_t* aSrc[NA];
  int aDst[NA];
#pragma unroll
  for (int q = 0; q < NA; ++q) {
    int r = w * (16 * NA) + q * 16 + (lane >> 2);          // M row in tile
    int cg = (lane & 3) ^ ((r >> 1) & 3);                  // swizzled K-granule
    aSrc[q] = A + (size_t)(m0 + r) * KDIM + cg * 8;
    aDst[q] = (w * NA + q) * 1024;                         // wave-uniform
  }
  const bf16_t* bSrc[2];
  int bDst[2];
#pragma unroll
  for (int q = 0; q < 2; ++q) {
    int r = w * 32 + q * 16 + (lane >> 2);                 // c row in tile
    int cg = (lane & 3) ^ ((r >> 1) & 3);
    if (MODE == 1) {
      int tok = inv[e * CAP + c0 + r];                     // pre-zeroed -> token 0 for empty
      bSrc[q] = Bbase + (size_t)tok * KDIM + cg * 8;
    } else {
      bSrc[q] = Bbase + (size_t)bz * ((size_t)CAP * KDIM) + (size_t)(c0 + r) * KDIM + cg * 8;
    }
    bDst[q] = ABYTES + (w * 2 + q) * 1024;
  }

  // ---- fragment LDS byte offsets (swizzled reads) ----
  int aoff[MF], boff[4];
#pragma unroll
  for (int mi = 0; mi < MF; ++mi) {
    int r = wm * (BM / 2) + mi * 16 + l15;
    aoff[mi] = r * 64 + ((l4 ^ ((r >> 1) & 3)) * 16);
  }
#pragma unroll
  for (int ni = 0; ni < 4; ++ni) {
    int r = wn * 64 + ni * 16 + l15;
    boff[ni] = ABYTES + r * 64 + ((l4 ^ ((r >> 1) & 3)) * 16);
  }

  f32x4 acc[MF][4];
#pragma unroll
  for (int mi = 0; mi < MF; ++mi)
#pragma unroll
    for (int ni = 0; ni < 4; ++ni) acc[mi][ni] = (f32x4){0.f, 0.f, 0.f, 0.f};

  auto stage = [&](int t) {
    char* s = smem + (size_t)(t & 3) * SLOT;
    int k = t * 32;
#pragma unroll
    for (int q = 0; q < NA; ++q) gload16(aSrc[q] + k, s + aDst[q]);
#pragma unroll
    for (int q = 0; q < 2; ++q) gload16(bSrc[q] + k, s + bDst[q]);
  };

  auto compute = [&](int t) {
    const char* s = smem + (size_t)(t & 3) * SLOT;
    bf16x8 af[MF], bv[4];
#pragma unroll
    for (int mi = 0; mi < MF; ++mi) af[mi] = *(const bf16x8*)(s + aoff[mi]);
#pragma unroll
    for (int ni = 0; ni < 4; ++ni) bv[ni] = *(const bf16x8*)(s + boff[ni]);
    __builtin_amdgcn_s_setprio(1);
#pragma unroll
    for (int mi = 0; mi < MF; ++mi)
#pragma unroll
      for (int ni = 0; ni < 4; ++ni)
        acc[mi][ni] = __builtin_amdgcn_mfma_f32_16x16x32_bf16(af[mi], bv[ni], acc[mi][ni], 0, 0, 0);
    __builtin_amdgcn_s_setprio(0);
  };

  // ---- pipeline: 3 tiles prefetched ahead; 2 raw barriers/phase, never vmcnt(0) in body ----
  stage(0); stage(1); stage(2);
  for (int j = 0; j < NT - 3; ++j) {
    stage(j + 3);                    // slot (j+3)&3 == slot (j-1)&3: freed at barrier#2 of j-1
    if constexpr (NA == 2) { VMWAIT(12); } else { VMWAIT(9); }   // tile j complete (mine)
    BARR;                            // ... and everyone else's
    compute(j);
    BARR;                            // slot j free for phase j+1's stage
  }
  if constexpr (NA == 2) { VMWAIT(8); } else { VMWAIT(6); }
  BARR; compute(NT - 3); BARR;
  if constexpr (NA == 2) { VMWAIT(4); } else { VMWAIT(3); }
  BARR; compute(NT - 2); BARR;
  VMWAIT(0);
  BARR; compute(NT - 1);

  // ---- epilogue: D layout col(c)=lane&15, row(m)=(lane>>4)*4+reg [verified m89/m91] ----
  if constexpr (MODE == 1) {
    bf16_t* h = (bf16_t*)outp + (size_t)bz * ((size_t)CAP * FDIM);
#pragma unroll
    for (int ni = 0; ni < 4; ++ni) {
      int c = c0 + wn * 64 + ni * 16 + l15;
      bf16_t* hrow = h + (size_t)c * FDIM;
#pragma unroll
      for (int mi = 0; mi < MF; ++mi) {
        int f = m0 + wm * (BM / 2) + mi * 16 + l4 * 4;
        const float4 bi = *(const float4*)&bias[f];
        f32x4 v = acc[mi][ni];
        bf16x4 hv;
        hv[0] = (bf16_t)fmaxf(v[0] + bi.x, 0.f);
        hv[1] = (bf16_t)fmaxf(v[1] + bi.y, 0.f);
        hv[2] = (bf16_t)fmaxf(v[2] + bi.z, 0.f);
        hv[3] = (bf16_t)fmaxf(v[3] + bi.w, 0.f);
        *(bf16x4*)&hrow[f] = hv;
      }
    }
  } else {
    float* finalp = (float*)outp;
#pragma unroll
    for (int ni = 0; ni < 4; ++ni) {
      int c = c0 + wn * 64 + ni * 16 + l15;
      if (c < cnt) {
        int tok = inv[e * CAP + c];
        float r = rpm[tok];
        float* orow = finalp + (size_t)tok * DDIM;
#pragma unroll
        for (int mi = 0; mi < MF; ++mi) {
          int d = m0 + wm * (BM / 2) + mi * 16 + l4 * 4;
          const float4 bi = *(const float4*)&bias[d];
          f32x4 v = acc[mi][ni];
          float4 o;
          o.x = (v[0] + bi.x) * r;
          o.y = (v[1] + bi.y) * r;
          o.z = (v[2] + bi.z) * r;
          o.w = (v[3] + bi.w) * r;
          *(float4*)&orow[d] = o;
        }
      }
    }
  }
}

// ---------------- host launcher ----------------
extern "C" void kernel_launch(void* const* d_in, const int* in_sizes, int n_in,
                              void* d_out, int out_size, void* d_ws, size_t ws_size,
                              hipStream_t stream) {
  (void)in_sizes; (void)n_in; (void)out_size;
  const float* x   = (const float*)d_in[0];
  const float* wsw = (const float*)d_in[1];
  const float* bsw = (const float*)d_in[2];
  const float* W1  = (const float*)d_in[3];
  const float* b1  = (const float*)d_in[4];
  const float* W2  = (const float*)d_in[5];
  const float* b2  = (const float*)d_in[6];

  float* out_final  = (float*)d_out;            // [T][D]
  float* out_counts = out_final + 8388608;      // [8]
  float* out_rps    = out_final + 8388616;      // [8]
  float* out_ndrop  = out_final + 8388624;      // [1]
  float* out_rpm    = out_final + 8388625;      // [T]

  char* ws = (char*)d_ws;
  size_t off = 0;
  auto carve = [&](size_t bytes) {
    char* p = ws + off;
    off += (bytes + 255) & ~(size_t)255;
    return p;
  };
  bf16_t* xbf     = (bf16_t*)carve((size_t)T_TOK * DDIM * 2);   // 16 MB
  int*    routes  = (int*)   carve((size_t)T_TOK * 4);
  int*    inv     = (int*)   carve((size_t)NEXP * CAP * 4);
  int*    counts_i= (int*)   carve((size_t)NEXP * 4);
  float*  partial = (float*) carve((size_t)2048 * 8 * 4);
  size_t fixed = off;
  const size_t PER_E = 2 * (size_t)FDIM * DDIM * 2 + (size_t)CAP * FDIM * 2; // W1T+W2T+h = 32MB
  int nb = 8;
  while (nb > 1 && fixed + (size_t)nb * PER_E > ws_size) nb >>= 1;
  bf16_t* W1T  = (bf16_t*)carve((size_t)nb * FDIM * DDIM * 2);
  bf16_t* W2T  = (bf16_t*)carve((size_t)nb * DDIM * FDIM * 2);
  bf16_t* hbuf = (bf16_t*)carve((size_t)nb * CAP * FDIM * 2);

  // >64KB dynamic LDS opt-in (runtime attr; not a stream op, graph-capture safe)
  hipFuncSetAttribute((const void*)gemm8_kernel<DDIM, 1, 256>,
                      hipFuncAttributeMaxDynamicSharedMemorySize, 4 * (256 * 64 + 16384));
  hipFuncSetAttribute((const void*)gemm8_kernel<FDIM, 2, 128>,
                      hipFuncAttributeMaxDynamicSharedMemorySize, 4 * (128 * 64 + 16384));

  conv_x_kernel<<<T_TOK * DDIM / 4 / 256, 256, 0, stream>>>(x, xbf);
  router_kernel<<<T_TOK / 4, 256, 0, stream>>>(x, wsw, bsw, routes, out_rpm, partial);
  reduce_partials_kernel<<<1, 256, 0, stream>>>(partial, out_rps);
  hipMemsetAsync(inv, 0, (size_t)NEXP * CAP * 4, stream);
  scan_kernel<<<1, 256, 0, stream>>>(routes, inv, counts_i, out_counts, out_ndrop);
  fill_passthrough_kernel<<<T_TOK * DDIM / 4 / 256, 256, 0, stream>>>(x, out_rpm, out_final);

  for (int e0 = 0; e0 < NEXP; e0 += nb) {
    // W1 [e][D][F] -> W1T [F][D] bf16
    transpose_conv_kernel<<<dim3(FDIM / 64, DDIM / 64, nb), 256, 0, stream>>>(W1, W1T, DDIM, FDIM, e0);
    gemm8_kernel<DDIM, 1, 256><<<dim3(CAP / 256, FDIM / 256, nb), 512,
                                 4 * (256 * 64 + 16384), stream>>>(
        W1T, xbf, inv, counts_i, b1, nullptr, hbuf, e0);
    // W2 [e][F][D] -> W2T [D][F] bf16
    transpose_conv_kernel<<<dim3(DDIM / 64, FDIM / 64, nb), 256, 0, stream>>>(W2, W2T, FDIM, DDIM, e0);
    gemm8_kernel<FDIM, 2, 128><<<dim3(CAP / 256, DDIM / 128, nb), 512,
                                 4 * (128 * 64 + 16384), stream>>>(
        W2T, hbuf, inv, counts_i, b2, out_rpm, d_out, e0);
  }
}

// Round 4
// 432.708 us; speedup vs baseline: 1.4109x; 1.0655x over previous
//
#include <hip/hip_runtime.h>
#include <hip/hip_bf16.h>
#include <cstdint>
#include <cstddef>

// Problem constants (fixed by reference)
#define T_TOK 8192
#define DDIM  1024
#define FDIM  4096
#define NEXP  8
#define CAP   2048   // int(2.0 * T / E)

typedef __bf16 bf16_t;
typedef __bf16 bf16x8 __attribute__((ext_vector_type(8)));
typedef __bf16 bf16x4 __attribute__((ext_vector_type(4)));
typedef float  f32x4  __attribute__((ext_vector_type(4)));

// async global->LDS, 16B per lane; lds dest is wave-uniform base + lane*16
__device__ __forceinline__ void gload16(const void* g, void* l) {
  __builtin_amdgcn_global_load_lds(
      (const __attribute__((address_space(1))) unsigned int*)g,
      (__attribute__((address_space(3))) unsigned int*)l,
      16, 0, 0);
}

#define VMWAIT(N) asm volatile("s_waitcnt vmcnt(" #N ")" ::: "memory")
#define BARR asm volatile("s_barrier" ::: "memory")

// ---------------- x fp32 -> bf16 ----------------
__global__ void conv_x_kernel(const float* __restrict__ x, bf16_t* __restrict__ xb) {
  int i = blockIdx.x * blockDim.x + threadIdx.x;   // float4 index, total T*D/4
  float4 v = ((const float4*)x)[i];
  bf16x4 o;
  o[0] = (bf16_t)v.x; o[1] = (bf16_t)v.y; o[2] = (bf16_t)v.z; o[3] = (bf16_t)v.w;
  *(bf16x4*)(xb + (size_t)i * 4) = o;
}

// ---------------- router: logits, softmax, argmax ----------------
__global__ void router_kernel(const float* __restrict__ x, const float* __restrict__ wsw,
                              const float* __restrict__ bsw, int* __restrict__ routes,
                              float* __restrict__ rpm, float* __restrict__ partial) {
  const int wv = threadIdx.x >> 6, lane = threadIdx.x & 63;
  const int t = blockIdx.x * 4 + wv;
  const float* xr = x + (size_t)t * DDIM;
  float a[8] = {0.f,0.f,0.f,0.f,0.f,0.f,0.f,0.f};
  for (int d = lane; d < DDIM; d += 64) {
    float xv = xr[d];
    const float4* wr = (const float4*)(wsw + d * 8);
    float4 w0 = wr[0], w1 = wr[1];
    a[0] += xv * w0.x; a[1] += xv * w0.y; a[2] += xv * w0.z; a[3] += xv * w0.w;
    a[4] += xv * w1.x; a[5] += xv * w1.y; a[6] += xv * w1.z; a[7] += xv * w1.w;
  }
#pragma unroll
  for (int e = 0; e < 8; ++e) {
#pragma unroll
    for (int off = 32; off > 0; off >>= 1) a[e] += __shfl_xor(a[e], off);
    a[e] += bsw[e];
  }
  float m = a[0]; int arg = 0;
#pragma unroll
  for (int e = 1; e < 8; ++e) { if (a[e] > m) { m = a[e]; arg = e; } }
  float p[8]; float s = 0.f;
#pragma unroll
  for (int e = 0; e < 8; ++e) { p[e] = expf(a[e] - m); s += p[e]; }
  float inv_s = 1.f / s;   // = softmax max since p[arg]=1
  __shared__ float pp[4][8];
  if (lane == 0) {
    routes[t] = arg;
    rpm[t] = inv_s;
#pragma unroll
    for (int e = 0; e < 8; ++e) pp[wv][e] = p[e] * inv_s;
  }
  __syncthreads();
  if (threadIdx.x < 8) {
    int e = threadIdx.x;
    partial[(size_t)blockIdx.x * 8 + e] = pp[0][e] + pp[1][e] + pp[2][e] + pp[3][e];
  }
}

// ---------------- deterministic reduce of per-block prob sums ----------------
__global__ void reduce_partials_kernel(const float* __restrict__ partial,
                                       float* __restrict__ out_rps) {
  int tid = threadIdx.x;           // 256
  int e = tid & 7, j0 = tid >> 3;  // 32 lanes per expert
  float s = 0.f;
  for (int j = j0; j < 2048; j += 32) s += partial[j * 8 + e];
  __shared__ float red[256];
  red[tid] = s;
  __syncthreads();
  if (tid < 8) {
    float t = 0.f;
    for (int k = 0; k < 32; ++k) t += red[tid + 8 * k];
    out_rps[tid] = t;
  }
}

// ---------------- queue-position scan + dispatch index build ----------------
__global__ void scan_kernel(const int* __restrict__ routes, int* __restrict__ inv,
                            int* __restrict__ counts_i, float* __restrict__ out_counts,
                            float* __restrict__ out_ndrop) {
  __shared__ int scnt[256][8];
  __shared__ int raw[8];
  int tid = threadIdx.x;
  int myr[32];
  int cnt[8] = {0,0,0,0,0,0,0,0};
  int tbase = tid * 32;
  for (int i = 0; i < 32; ++i) { int r = routes[tbase + i]; myr[i] = r; cnt[r]++; }
#pragma unroll
  for (int e = 0; e < 8; ++e) scnt[tid][e] = cnt[e];
  __syncthreads();
  if (tid < 8) {
    int run = 0;
    for (int j = 0; j < 256; ++j) { int v = scnt[j][tid]; scnt[j][tid] = run; run += v; }
    raw[tid] = run;
  }
  __syncthreads();
  int base[8];
#pragma unroll
  for (int e = 0; e < 8; ++e) base[e] = scnt[tid][e];
  for (int i = 0; i < 32; ++i) {
    int r = myr[i];
    int p = base[r]++;
    if (p < CAP) inv[r * CAP + p] = tbase + i;
  }
  if (tid < 8) {
    int c = min(raw[tid], CAP);
    counts_i[tid] = c;
    out_counts[tid] = (float)c;
  }
  if (tid == 0) {
    int kept = 0;
    for (int e = 0; e < 8; ++e) kept += min(raw[e], CAP);
    *out_ndrop = (float)(T_TOK - kept);
  }
}

// ---------------- transpose + fp32->bf16 convert (per expert slice) ----------------
__global__ void transpose_conv_kernel(const float* __restrict__ src, bf16_t* __restrict__ dst,
                                      int R, int C, int e0) {
  const float* s = src + (size_t)(e0 + blockIdx.z) * ((size_t)R * C);
  bf16_t* d = dst + (size_t)blockIdx.z * ((size_t)R * C);
  __shared__ float tile[64][65];
  int bx = blockIdx.x * 64, by = blockIdx.y * 64;   // bx over C, by over R
  int c4 = (threadIdx.x & 15) * 4;
  int r0 = threadIdx.x >> 4;        // 16 rows per pass, 4 passes
#pragma unroll
  for (int p = 0; p < 4; ++p) {
    int r = r0 + p * 16;
    float4 v = *(const float4*)&s[(size_t)(by + r) * C + bx + c4];
    tile[r][c4] = v.x; tile[r][c4 + 1] = v.y; tile[r][c4 + 2] = v.z; tile[r][c4 + 3] = v.w;
  }
  __syncthreads();
  int r8 = (threadIdx.x & 7) * 8;
  int cw = threadIdx.x >> 3;        // 32 cols per pass, 2 passes
#pragma unroll
  for (int p = 0; p < 2; ++p) {
    int c = cw + p * 32;
    bf16x8 o;
#pragma unroll
    for (int j = 0; j < 8; ++j) o[j] = (bf16_t)tile[r8 + j][c];
    *(bf16x8*)&d[(size_t)(bx + c) * R + by + r8] = o;
  }
}

// ---------------- pass-through fill: final[t] = x[t] * rpm[t] ----------------
__global__ void fill_passthrough_kernel(const float* __restrict__ x, const float* __restrict__ rpm,
                                        float* __restrict__ outf) {
  int i = blockIdx.x * blockDim.x + threadIdx.x;   // float4 index
  int t = i >> 8;                                  // 256 float4 per row
  float r = rpm[t];
  float4 v = ((const float4*)x)[i];
  float4 o = {v.x * r, v.y * r, v.z * r, v.w * r};
  ((float4*)outf)[i] = o;
}

// ============ MFMA GEMM: m201/m248-style 8-phase, BK=64, 2 K-tiles/iter ============
// D[m][c] = sum_k A[m][k] * B[c][k]  (row-major K-contiguous operands)
// 8 waves = 2M x 4N; per-wave output (BM/2) x 64 with interleaved 16-row frags:
//   A row of (wm, mi) = m0 + (mi*2+wm)*16 ; B col of (wn, nj) = c0 + (nj*4+wn)*16
// LDS: A[2buf][2 Mhalf][BM/2 rows][64K swz]  B[2buf][2 kstep][256 cols][32K swz]
// Phase p of iter (t0=2i,t1=2i+1):   (reads | stage-unit | wait)
//  P1: A(h0,k0)+B(k0) buf0 | Ah1(t1)   |        P5: buf1 ... | Ah1(t2) |
//  P2: A(h1,k0)       buf0 | Bk1(t1)   |        P6: ...      | Bk1(t2) |
//  P3: A(h0,k1)+B(k1) buf0 | Bk0(t2)   |        P7: ...      | Bk0(t3) |
//  P4: A(h1,k1)       buf0 | Ah0(t2)   | VM(LA+LB)   P8: ... | Ah0(t3) | VM(LA+LB)
// Each phase: reads, stage, [wait], barrier, lgkmcnt(0)+sched_barrier, setprio(1),
// 16(=MF2*4) MFMA, setprio(0), barrier.  vmcnt never drained to 0 in steady state.
// Swizzle: A granule (16B of 8 in 128B row) j = kg ^ (row&7); B granule (of 4 in
// 64B row) j = kg ^ (col&3). Content pre-swizzled at the GLOBAL source (gload_lds
// writes linearly); reads apply the same XOR. Measured 0 conflicts for this family.
template <int KDIM, int MODE, int BM>
__launch_bounds__(512, 2)
__global__ void gemm8p_kernel(const bf16_t* __restrict__ Abase, const bf16_t* __restrict__ Bbase,
                              const int* __restrict__ inv, const int* __restrict__ counts_i,
                              const float* __restrict__ bias_all, const float* __restrict__ rpm,
                              void* __restrict__ outp, int e0) {
  constexpr int MDIM = (MODE == 1) ? FDIM : DDIM;
  constexpr int NT = KDIM / 64;          // K-tiles
  constexpr int MF = BM / 32;            // M-frags per wave (8 or 4)
  constexpr int MF2 = MF / 2;
  constexpr int LA = BM / 128;           // gloads/thread per A-half unit (2 or 1)
  constexpr int AH = (BM / 2) * 128;     // A-half bytes
  constexpr int ABASE = 4 * AH;          // B region start
  extern __shared__ char smem[];

  // T1: XCD-chunked bijective swizzle (nwg % 8 == 0 by construction)
  const int nx = gridDim.x, ny = gridDim.y;
  const int nwg = nx * ny * gridDim.z;
  const int flat = blockIdx.x + nx * (blockIdx.y + ny * blockIdx.z);
  const int nf = (flat & 7) * (nwg >> 3) + (flat >> 3);
  const int bx = nf % nx;
  const int tmp = nf / nx;
  const int by = tmp % ny, bz = tmp / ny;

  const int e = e0 + bz;
  const int cnt = counts_i[e];
  const int c0 = bx * 256;
  if (c0 >= cnt) return;                 // uniform early-exit before any barrier
  const int m0 = by * BM;

  const bf16_t* A = Abase + (size_t)bz * ((size_t)MDIM * KDIM);
  const float* bias = bias_all + (size_t)e * MDIM;

  const int tid = threadIdx.x, lane = tid & 63, w = tid >> 6;
  const int l15 = lane & 15, l4 = lane >> 4;
  const int wm = w >> 2, wn = w & 3;

  // ---- stage sources (pre-swizzled global addresses) ----
  // A: thread covers half-local row lr, granule slot j; content granule kg = j ^ (lr&7)
  size_t aSrcOff[LA];
#pragma unroll
  for (int q = 0; q < LA; ++q) {
    int lr = (w * LA + q) * 8 + (lane >> 3);
    int kg = (lane & 7) ^ (lr & 7);
    aSrcOff[q] = (size_t)(m0 + lr) * KDIM + kg * 8;
  }
  // B: thread covers col cb, slot j of 4; content granule kg2 = j ^ (cb&3)
  const bf16_t* bSrcPtr[2];
#pragma unroll
  for (int q = 0; q < 2; ++q) {
    int cb = (w * 2 + q) * 16 + (lane >> 2);
    int kg2 = (lane & 3) ^ (cb & 3);
    if (MODE == 1) {
      int tok = inv[e * CAP + c0 + cb];  // pre-zeroed -> token 0 for empty slots
      bSrcPtr[q] = Bbase + (size_t)tok * KDIM + kg2 * 8;
    } else {
      bSrcPtr[q] = Bbase + (size_t)bz * ((size_t)CAP * KDIM) + (size_t)(c0 + cb) * KDIM + kg2 * 8;
    }
  }

  // ---- swizzled read offsets ----
  int aRd[MF2][2];
#pragma unroll
  for (int m2 = 0; m2 < MF2; ++m2) {
    int lr = (m2 * 2 + wm) * 16 + l15;
#pragma unroll
    for (int s = 0; s < 2; ++s)
      aRd[m2][s] = lr * 128 + (((s * 4 + l4) ^ (lr & 7)) << 4);
  }
  int bRd[4];
#pragma unroll
  for (int nj = 0; nj < 4; ++nj) {
    int cb = (nj * 4 + wn) * 16 + l15;
    bRd[nj] = cb * 64 + ((l4 ^ (cb & 3)) << 4);
  }

  auto stageA = [&](int t, int h) {
    char* base = smem + ((t & 1) * 2 + h) * AH;
#pragma unroll
    for (int q = 0; q < LA; ++q)
      gload16(A + aSrcOff[q] + (size_t)h * (size_t)(BM / 2) * KDIM + t * 64,
              base + (w * LA + q) * 1024);
  };
  auto stageB = [&](int t, int s) {
    char* base = smem + ABASE + (t & 1) * 32768 + s * 16384;
#pragma unroll
    for (int q = 0; q < 2; ++q)
      gload16(bSrcPtr[q] + t * 64 + s * 32, base + (w * 2 + q) * 1024);
  };

  f32x4 acc[MF][4];
#pragma unroll
  for (int i = 0; i < MF; ++i)
#pragma unroll
    for (int j = 0; j < 4; ++j) acc[i][j] = (f32x4){0.f, 0.f, 0.f, 0.f};
  bf16x8 bv[4];

#define WAITSTEADY do { if constexpr (LA == 2) { VMWAIT(4); } else { VMWAIT(3); } } while (0)

#define PHASE(BUF, S, MH, DOB, STAGE, WAITC)                                    \
  {                                                                             \
    const char* sa_ = smem + ((BUF) * 2 + (MH)) * AH;                           \
    bf16x8 af_[MF2];                                                            \
    _Pragma("unroll") for (int m2 = 0; m2 < MF2; ++m2)                          \
        af_[m2] = *(const bf16x8*)(sa_ + aRd[m2][S]);                           \
    if (DOB) {                                                                  \
      const char* sb_ = smem + ABASE + (BUF) * 32768 + (S) * 16384;             \
      _Pragma("unroll") for (int nj = 0; nj < 4; ++nj)                          \
          bv[nj] = *(const bf16x8*)(sb_ + bRd[nj]);                             \
    }                                                                           \
    STAGE;                                                                      \
    WAITC;                                                                      \
    BARR;                                                                       \
    asm volatile("s_waitcnt lgkmcnt(0)" ::: "memory");                          \
    __builtin_amdgcn_sched_barrier(0);                                          \
    __builtin_amdgcn_s_setprio(1);                                              \
    _Pragma("unroll") for (int m2 = 0; m2 < MF2; ++m2)                          \
      _Pragma("unroll") for (int nj = 0; nj < 4; ++nj)                          \
          acc[(MH) * MF2 + m2][nj] = __builtin_amdgcn_mfma_f32_16x16x32_bf16(   \
              af_[m2], bv[nj], acc[(MH) * MF2 + m2][nj], 0, 0, 0);              \
    __builtin_amdgcn_s_setprio(0);                                              \
    BARR;                                                                       \
  }

  // ---- prologue: t0 fully + t1:{Ah0, Bk0}; leave exactly LA+LB outstanding ----
  stageA(0, 0); stageA(0, 1); stageB(0, 0); stageB(0, 1);
  stageA(1, 0); stageB(1, 0);
  WAITSTEADY;
  BARR;

  for (int i = 0; i < NT / 2; ++i) {
    const int t1 = 2 * i + 1, t2 = 2 * i + 2, t3 = 2 * i + 3;
    const bool more = (t2 < NT);
    PHASE(0, 0, 0, true,  { stageA(t1, 1); }, {});
    PHASE(0, 0, 1, false, { stageB(t1, 1); }, {});
    PHASE(0, 1, 0, true,  { if (more) stageB(t2, 0); }, {});
    PHASE(0, 1, 1, false, { if (more) stageA(t2, 0); },
          { if (more) { WAITSTEADY; } else { VMWAIT(0); } });
    PHASE(1, 0, 0, true,  { if (more) stageA(t2, 1); }, {});
    PHASE(1, 0, 1, false, { if (more) stageB(t2, 1); }, {});
    PHASE(1, 1, 0, true,  { if (more) stageB(t3, 0); }, {});
    PHASE(1, 1, 1, false, { if (more) stageA(t3, 0); },
          { if (more) { WAITSTEADY; } else { VMWAIT(0); } });
  }
#undef PHASE
#undef WAITSTEADY

  // ---- epilogue: D layout col=lane&15, row=(lane>>4)*4+reg [m89/m91] ----
  // frag (wm,mi),(wn,nj): out-M = m0+(mi*2+wm)*16+l4*4+v ; out-col = c0+(nj*4+wn)*16+l15
  if constexpr (MODE == 1) {
    bf16_t* h = (bf16_t*)outp + (size_t)bz * ((size_t)CAP * FDIM);
#pragma unroll
    for (int nj = 0; nj < 4; ++nj) {
      int c = c0 + (nj * 4 + wn) * 16 + l15;
      bf16_t* hrow = h + (size_t)c * FDIM;
#pragma unroll
      for (int mi = 0; mi < MF; ++mi) {
        int f = m0 + (mi * 2 + wm) * 16 + l4 * 4;
        const float4 bi = *(const float4*)&bias[f];
        f32x4 v = acc[mi][nj];
        bf16x4 hv;
        hv[0] = (bf16_t)fmaxf(v[0] + bi.x, 0.f);
        hv[1] = (bf16_t)fmaxf(v[1] + bi.y, 0.f);
        hv[2] = (bf16_t)fmaxf(v[2] + bi.z, 0.f);
        hv[3] = (bf16_t)fmaxf(v[3] + bi.w, 0.f);
        *(bf16x4*)&hrow[f] = hv;
      }
    }
  } else {
    float* finalp = (float*)outp;
#pragma unroll
    for (int nj = 0; nj < 4; ++nj) {
      int c = c0 + (nj * 4 + wn) * 16 + l15;
      if (c < cnt) {
        int tok = inv[e * CAP + c];
        float r = rpm[tok];
        float* orow = finalp + (size_t)tok * DDIM;
#pragma unroll
        for (int mi = 0; mi < MF; ++mi) {
          int d = m0 + (mi * 2 + wm) * 16 + l4 * 4;
          const float4 bi = *(const float4*)&bias[d];
          f32x4 v = acc[mi][nj];
          float4 o;
          o.x = (v[0] + bi.x) * r;
          o.y = (v[1] + bi.y) * r;
          o.z = (v[2] + bi.z) * r;
          o.w = (v[3] + bi.w) * r;
          *(float4*)&orow[d] = o;
        }
      }
    }
  }
}

// ---------------- host launcher ----------------
extern "C" void kernel_launch(void* const* d_in, const int* in_sizes, int n_in,
                              void* d_out, int out_size, void* d_ws, size_t ws_size,
                              hipStream_t stream) {
  (void)in_sizes; (void)n_in; (void)out_size;
  const float* x   = (const float*)d_in[0];
  const float* wsw = (const float*)d_in[1];
  const float* bsw = (const float*)d_in[2];
  const float* W1  = (const float*)d_in[3];
  const float* b1  = (const float*)d_in[4];
  const float* W2  = (const float*)d_in[5];
  const float* b2  = (const float*)d_in[6];

  float* out_final  = (float*)d_out;            // [T][D]
  float* out_counts = out_final + 8388608;      // [8]
  float* out_rps    = out_final + 8388616;      // [8]
  float* out_ndrop  = out_final + 8388624;      // [1]
  float* out_rpm    = out_final + 8388625;      // [T]

  char* ws = (char*)d_ws;
  size_t off = 0;
  auto carve = [&](size_t bytes) {
    char* p = ws + off;
    off += (bytes + 255) & ~(size_t)255;
    return p;
  };
  bf16_t* xbf     = (bf16_t*)carve((size_t)T_TOK * DDIM * 2);   // 16 MB
  int*    routes  = (int*)   carve((size_t)T_TOK * 4);
  int*    inv     = (int*)   carve((size_t)NEXP * CAP * 4);
  int*    counts_i= (int*)   carve((size_t)NEXP * 4);
  float*  partial = (float*) carve((size_t)2048 * 8 * 4);
  size_t fixed = off;
  const size_t PER_E = 2 * (size_t)FDIM * DDIM * 2 + (size_t)CAP * FDIM * 2; // W1T+W2T+h = 32MB
  int nb = 8;
  while (nb > 1 && fixed + (size_t)nb * PER_E > ws_size) nb >>= 1;
  bf16_t* W1T  = (bf16_t*)carve((size_t)nb * FDIM * DDIM * 2);
  bf16_t* W2T  = (bf16_t*)carve((size_t)nb * DDIM * FDIM * 2);
  bf16_t* hbuf = (bf16_t*)carve((size_t)nb * CAP * FDIM * 2);

  // >64KB dynamic LDS opt-in (runtime attr; graph-capture safe)
  hipFuncSetAttribute((const void*)gemm8p_kernel<DDIM, 1, 256>,
                      hipFuncAttributeMaxDynamicSharedMemorySize, 131072);
  hipFuncSetAttribute((const void*)gemm8p_kernel<FDIM, 2, 128>,
                      hipFuncAttributeMaxDynamicSharedMemorySize, 98304);

  conv_x_kernel<<<T_TOK * DDIM / 4 / 256, 256, 0, stream>>>(x, xbf);
  router_kernel<<<T_TOK / 4, 256, 0, stream>>>(x, wsw, bsw, routes, out_rpm, partial);
  reduce_partials_kernel<<<1, 256, 0, stream>>>(partial, out_rps);
  hipMemsetAsync(inv, 0, (size_t)NEXP * CAP * 4, stream);
  scan_kernel<<<1, 256, 0, stream>>>(routes, inv, counts_i, out_counts, out_ndrop);
  fill_passthrough_kernel<<<T_TOK * DDIM / 4 / 256, 256, 0, stream>>>(x, out_rpm, out_final);

  for (int e0 = 0; e0 < NEXP; e0 += nb) {
    // W1 [e][D][F] -> W1T [F][D] bf16
    transpose_conv_kernel<<<dim3(FDIM / 64, DDIM / 64, nb), 256, 0, stream>>>(W1, W1T, DDIM, FDIM, e0);
    gemm8p_kernel<DDIM, 1, 256><<<dim3(CAP / 256, FDIM / 256, nb), 512, 131072, stream>>>(
        W1T, xbf, inv, counts_i, b1, nullptr, hbuf, e0);
    // W2 [e][F][D] -> W2T [D][F] bf16
    transpose_conv_kernel<<<dim3(DDIM / 64, FDIM / 64, nb), 256, 0, stream>>>(W2, W2T, FDIM, DDIM, e0);
    gemm8p_kernel<FDIM, 2, 128><<<dim3(CAP / 256, DDIM / 128, nb), 512, 98304, stream>>>(
        W2T, hbuf, inv, counts_i, b2, out_rpm, d_out, e0);
  }
}